// Round 17
// baseline (24.308 us; speedup 1.0000x reference)
//
#include <hip/hip_runtime.h>
#include <hip/hip_bf16.h>

typedef __attribute__((ext_vector_type(8))) short bf16x8;
typedef __attribute__((ext_vector_type(4))) float f32x4;

#define NBLK 256   // blocks; 512 threads (8 waves); 1 block/CU (88 KB LDS), 2 waves/SIMD

__device__ __forceinline__ unsigned short f2bf(float f) {
    unsigned u = __float_as_uint(f);
    return (unsigned short)((u + 0x7fffu + ((u >> 16) & 1u)) >> 16);
}

__device__ __forceinline__ bf16x8 pack8(float4 x, float4 y) {
    bf16x8 r;
    r[0] = (short)f2bf(x.x); r[1] = (short)f2bf(x.y);
    r[2] = (short)f2bf(x.z); r[3] = (short)f2bf(x.w);
    r[4] = (short)f2bf(y.x); r[5] = (short)f2bf(y.y);
    r[6] = (short)f2bf(y.z); r[7] = (short)f2bf(y.w);
    return r;
}

__device__ __forceinline__ float ftanh(float x) {
    float e = __expf(2.f * x);
    return 1.f - 2.f / (e + 1.f);
}

// R16 kernel (masked-fused + in-wave ballot sort, 24.1us) RESCHEDULED for
// latency overlap (both phases latency-bound at 2 waves/SIMD):
//  (1) ij load + sort + all-tile index shfl + tile-0 desc loads issued BEFORE
//      weight staging -> cold-miss chain drains under the staging loop;
//  (2) tile tp+1 desc loads issue before tile tp compute (manual rotation);
//  (3) bias hoisted to registers.
// NOTE (R13/R14): block-level LDS binning regressed 10x — do not revisit.
// Layout (verified R1-R5): A row=lane&15, k=(lane>>4)*8+j; B col=lane&15
// (edge), same k; D col=lane&15 (edge), row=(lane>>4)*4+r -> f32x4 store/nt.
__global__ __launch_bounds__(512, 2) void k_fused(
    const int* __restrict__ ij, const float* __restrict__ desc,
    const float* __restrict__ layer1, const float* __restrict__ lin_w,
    const float* __restrict__ lin_b, float* __restrict__ out, int E) {

    __shared__ __align__(16) short wsm[11 * 512 * 8];   // 88 KiB; m=10 is lin_w

    const int lane = threadIdx.x & 63;
    const int col = lane & 15;
    const int g = lane >> 4;
    const int kb = g * 8;
    const bf16x8 zero8 = {0, 0, 0, 0, 0, 0, 0, 0};

    const int gw = blockIdx.x * 8 + (threadIdx.x >> 6);
    const int base = gw * 64;
    const bool active = base < E;

    // ---- phase 0 (pre-staging): ij -> sort -> tile indices -> tile-0 desc ----
    int e_arr[4], ty_arr[4], lo[4], hi[4];
    float4 cx0, cy0, cx1, cy1;
    if (active) {
        const int e_own = min(base + lane, E - 1);
        const int ty_own = ij[e_own];
        int rank = 0, below = 0;
        #pragma unroll
        for (int t = 0; t < 10; ++t) {
            const unsigned long long m = __ballot(ty_own == t);
            if (ty_own == t) rank = below + (int)__popcll(m & ((1ull << lane) - 1ull));
            below += (int)__popcll(m);
        }
        const int e_sorted = __builtin_amdgcn_ds_permute(rank << 2, e_own);
        const int ty_sorted = __builtin_amdgcn_ds_permute(rank << 2, ty_own);
        #pragma unroll
        for (int tp = 0; tp < 4; ++tp) {
            e_arr[tp] = __shfl(e_sorted, tp * 16 + col);
            ty_arr[tp] = __shfl(ty_sorted, tp * 16 + col);
            lo[tp] = __shfl(ty_sorted, tp * 16);
            hi[tp] = __shfl(ty_sorted, tp * 16 + 15);
        }
        const float* dp = desc + (size_t)e_arr[0] * 64 + kb;
        cx0 = *(const float4*)dp;        cy0 = *(const float4*)(dp + 4);
        cx1 = *(const float4*)(dp + 32); cy1 = *(const float4*)(dp + 36);
    }
    float4 bias[4];
    #pragma unroll
    for (int nt = 0; nt < 4; ++nt) bias[nt] = *(const float4*)(lin_b + nt * 16 + g * 4);

    // ---- weight staging (overlaps the in-flight loads above) ----
    for (int idx = threadIdx.x; idx < 11 * 512; idx += 512) {
        const int m = idx >> 9;
        const int fl = idx & 511;
        const int fi = fl >> 6, l = fl & 63;
        const int nt = fi >> 1, kk = fi & 1;
        const float* src = (m < 10) ? (layer1 + m * 4096) : lin_w;
        const float* sp = src + (nt * 16 + (l & 15)) * 64 + kk * 32 + (l >> 4) * 8;
        float4 x = *(const float4*)sp;
        float4 y = *(const float4*)(sp + 4);
        *(bf16x8*)(&wsm[idx * 8]) = pack8(x, y);
    }
    __syncthreads();

    if (!active) return;

    // lin fragments resident in registers (m=10 staged frags)
    bf16x8 al[4][2];
    #pragma unroll
    for (int fi = 0; fi < 8; ++fi)
        al[fi >> 1][fi & 1] = *(const bf16x8*)(&wsm[((80 + fi) * 64 + lane) * 8]);

    // ---- 4 sorted 16-edge tiles, next-tile desc prefetch ----
    #pragma unroll 1
    for (int tp = 0; tp < 4; ++tp) {
        float4 nx0, ny0, nx1, ny1;
        if (tp < 3) {
            const float* np = desc + (size_t)e_arr[tp + 1] * 64 + kb;
            nx0 = *(const float4*)np;        ny0 = *(const float4*)(np + 4);
            nx1 = *(const float4*)(np + 32); ny1 = *(const float4*)(np + 36);
        }
        const bf16x8 b0 = pack8(cx0, cy0);
        const bf16x8 b1 = pack8(cx1, cy1);
        const int ty_t = ty_arr[tp];

        f32x4 zL[4], zW[4];
        #pragma unroll
        for (int nt = 0; nt < 4; ++nt) {
            f32x4 z = {0.f, 0.f, 0.f, 0.f};
            z = __builtin_amdgcn_mfma_f32_16x16x32_bf16(al[nt][0], b0, z, 0, 0, 0);
            zL[nt] = __builtin_amdgcn_mfma_f32_16x16x32_bf16(al[nt][1], b1, z, 0, 0, 0);
            zW[nt] = (f32x4){0.f, 0.f, 0.f, 0.f};
        }

        #pragma unroll 1
        for (int m = lo[tp]; m <= hi[tp]; ++m) {
            if (!__any(ty_t == m)) continue;
            const bf16x8 m0 = (ty_t == m) ? b0 : zero8;
            const bf16x8 m1 = (ty_t == m) ? b1 : zero8;
            #pragma unroll
            for (int nt = 0; nt < 4; ++nt) {
                const bf16x8 f0 = *(const bf16x8*)(&wsm[((m * 8 + nt * 2 + 0) * 64 + lane) * 8]);
                const bf16x8 f1 = *(const bf16x8*)(&wsm[((m * 8 + nt * 2 + 1) * 64 + lane) * 8]);
                zW[nt] = __builtin_amdgcn_mfma_f32_16x16x32_bf16(f0, m0, zW[nt], 0, 0, 0);
                zW[nt] = __builtin_amdgcn_mfma_f32_16x16x32_bf16(f1, m1, zW[nt], 0, 0, 0);
            }
        }

        float* op = out + (size_t)e_arr[tp] * 64 + g * 4;
        #pragma unroll
        for (int nt = 0; nt < 4; ++nt) {
            f32x4 r;
            r[0] = ftanh(zW[nt][0]) + zL[nt][0] + bias[nt].x;
            r[1] = ftanh(zW[nt][1]) + zL[nt][1] + bias[nt].y;
            r[2] = ftanh(zW[nt][2]) + zL[nt][2] + bias[nt].z;
            r[3] = ftanh(zW[nt][3]) + zL[nt][3] + bias[nt].w;
            *(f32x4*)(op + nt * 16) = r;
        }

        cx0 = nx0; cy0 = ny0; cx1 = nx1; cy1 = ny1;
    }
}

extern "C" void kernel_launch(void* const* d_in, const int* in_sizes, int n_in,
                              void* d_out, int out_size, void* d_ws, size_t ws_size,
                              hipStream_t stream) {
    const int* ij = (const int*)d_in[0];
    const float* desc = (const float*)d_in[1];
    const float* layer1 = (const float*)d_in[2];
    const float* lin_w = (const float*)d_in[3];
    const float* lin_b = (const float*)d_in[4];
    float* out = (float*)d_out;
    const int E = in_sizes[0];

    k_fused<<<NBLK, 512, 0, stream>>>(ij, desc, layer1, lin_w, lin_b, out, E);
}